// Round 1
// baseline (583.176 us; speedup 1.0000x reference)
//
#include <hip/hip_runtime.h>
#include <stdint.h>

// Problem constants (fixed by reference: x[8192,4096], w[4096,4096], bias[4096])
#define NROW 8192
#define KDIM 4096
#define NOUT 4096
#define KW   (KDIM / 32)   // 128 packed u32 words per row

// ---------------------------------------------------------------------------
// Kernel 1: sign-binarize. bit j of word = (x[j] < 0). One wave handles 64
// consecutive floats per iter via __ballot (64-bit on CDNA), producing 2 u32.
// ---------------------------------------------------------------------------
__global__ __launch_bounds__(256)
void bin_sign_kernel(const float* __restrict__ x, uint32_t* __restrict__ xb, int nseg) {
    const int lane = threadIdx.x & 63;
    const int wpb  = blockDim.x >> 6;
    int w = blockIdx.x * wpb + (threadIdx.x >> 6);
    const int stride = gridDim.x * wpb;
    for (; w < nseg; w += stride) {
        float v = x[(size_t)w * 64 + lane];
        unsigned long long m = __ballot(v < 0.0f);
        if (lane == 0)  xb[2 * w]     = (uint32_t)m;
        if (lane == 32) xb[2 * w + 1] = (uint32_t)(m >> 32);
    }
}

// ---------------------------------------------------------------------------
// Kernel 2: XNOR-popcount GEMM.
//   C[n,o] = KDIM - 2 * sum_k popc(xb[n,k] ^ wb[o,k]) + bias[o]
// 128x128 tile per 256-thread block, 8x8 outputs per thread, BK=32 words.
// LDS stored transposed [k][row] so per-k fragments are contiguous
// -> 4x ds_read_b128 per 128 VALU (xor+bcnt) instructions.
// ---------------------------------------------------------------------------
#define BM 128
#define BN 128
#define BK 32

__global__ __launch_bounds__(256)
void xnor_gemm_kernel(const uint32_t* __restrict__ xb, const uint32_t* __restrict__ wb,
                      const float* __restrict__ bias, float* __restrict__ out) {
    __shared__ __align__(16) uint32_t la[BK][BM];
    __shared__ __align__(16) uint32_t lb[BK][BN];

    const int tid  = threadIdx.x;
    const int tx   = tid & 15;   // col group (8 cols)
    const int ty   = tid >> 4;   // row group (8 rows)
    const int row0 = blockIdx.y * BM;
    const int col0 = blockIdx.x * BN;

    // Staging: 2 threads per tile-row, 16 consecutive words (4x uint4) each.
    const int srow = tid >> 1;
    const int sseg = (tid & 1) * 16;

    const uint32_t* gA = xb + (size_t)(row0 + srow) * KW + sseg;
    const uint32_t* gB = wb + (size_t)(col0 + srow) * KW + sseg;

    uint32_t acc[8][8];
#pragma unroll
    for (int i = 0; i < 8; ++i)
#pragma unroll
        for (int j = 0; j < 8; ++j) acc[i][j] = 0;

    // Prefetch chunk 0 into registers.
    uint4 a4[4], b4[4];
#pragma unroll
    for (int i = 0; i < 4; ++i) a4[i] = ((const uint4*)gA)[i];
#pragma unroll
    for (int i = 0; i < 4; ++i) b4[i] = ((const uint4*)gB)[i];

    for (int kb = 0; kb < KW; kb += BK) {
        __syncthreads();   // previous chunk's compute reads done before overwrite
#pragma unroll
        for (int i = 0; i < 4; ++i) {
            la[sseg + i * 4 + 0][srow] = a4[i].x;
            la[sseg + i * 4 + 1][srow] = a4[i].y;
            la[sseg + i * 4 + 2][srow] = a4[i].z;
            la[sseg + i * 4 + 3][srow] = a4[i].w;
            lb[sseg + i * 4 + 0][srow] = b4[i].x;
            lb[sseg + i * 4 + 1][srow] = b4[i].y;
            lb[sseg + i * 4 + 2][srow] = b4[i].z;
            lb[sseg + i * 4 + 3][srow] = b4[i].w;
        }
        __syncthreads();

        // Issue next chunk's global loads now; latency hides behind compute.
        if (kb + BK < KW) {
            const uint32_t* pA = gA + kb + BK;
            const uint32_t* pB = gB + kb + BK;
#pragma unroll
            for (int i = 0; i < 4; ++i) a4[i] = ((const uint4*)pA)[i];
#pragma unroll
            for (int i = 0; i < 4; ++i) b4[i] = ((const uint4*)pB)[i];
        }

#pragma unroll 4
        for (int k = 0; k < BK; ++k) {
            uint32_t af[8], bf[8];
            *(uint4*)&af[0] = *(const uint4*)&la[k][ty * 8];
            *(uint4*)&af[4] = *(const uint4*)&la[k][ty * 8 + 4];
            *(uint4*)&bf[0] = *(const uint4*)&lb[k][tx * 8];
            *(uint4*)&bf[4] = *(const uint4*)&lb[k][tx * 8 + 4];
#pragma unroll
            for (int i = 0; i < 8; ++i)
#pragma unroll
                for (int j = 0; j < 8; ++j)
                    acc[i][j] += __popc(af[i] ^ bf[j]);
        }
    }

    float bv[8];
#pragma unroll
    for (int j = 0; j < 8; ++j) bv[j] = bias[col0 + tx * 8 + j];

#pragma unroll
    for (int i = 0; i < 8; ++i) {
        const int r = row0 + ty * 8 + i;
        float* po = out + (size_t)r * NOUT + col0 + tx * 8;
        float o[8];
#pragma unroll
        for (int j = 0; j < 8; ++j)
            o[j] = (float)(KDIM - 2 * (int)acc[i][j]) + bv[j];
        ((float4*)po)[0] = make_float4(o[0], o[1], o[2], o[3]);
        ((float4*)po)[1] = make_float4(o[4], o[5], o[6], o[7]);
    }
}

// ---------------------------------------------------------------------------
extern "C" void kernel_launch(void* const* d_in, const int* in_sizes, int n_in,
                              void* d_out, int out_size, void* d_ws, size_t ws_size,
                              hipStream_t stream) {
    const float* x  = (const float*)d_in[0];   // [8192, 4096]
    const float* w  = (const float*)d_in[1];   // [4096, 4096]
    const float* b  = (const float*)d_in[2];   // [4096]
    float* out = (float*)d_out;                // [8192, 4096]

    uint32_t* xb = (uint32_t*)d_ws;                 // 4 MiB
    uint32_t* wb = xb + (size_t)NROW * KW;          // +2 MiB

    bin_sign_kernel<<<2048, 256, 0, stream>>>(x, xb, NROW * KDIM / 64);
    bin_sign_kernel<<<1024, 256, 0, stream>>>(w, wb, NOUT * KDIM / 64);

    dim3 grid(NOUT / BN, NROW / BM);
    xnor_gemm_kernel<<<grid, 256, 0, stream>>>(xb, wb, b, out);
}